// Round 8
// baseline (2076.591 us; speedup 1.0000x reference)
//
#include <hip/hip_runtime.h>
#include <stdint.h>

// B=32, T=128, DIN=DOUT=1024. Input dtypes detected at runtime (bf16 vs fp32).
typedef unsigned short u16;
typedef unsigned long long u64;
typedef __attribute__((ext_vector_type(8))) short short8;   // 8 x bf16 MFMA operand
typedef __attribute__((ext_vector_type(4))) float f32x4;    // MFMA accumulator

// ---- workspace layout (bytes) ----
// Anti-contention layout (R5, kept): barrier flags strided 1KB with 4 replicas
// 256B apart; h and r*h tile buffers replicated 4x.
#define CNT_OFF    0                          // barrier flags: 64 x 1KB (zeroed)
#define FLG_OFF    131072                     // 13 dtype flags
#define BS_OFF     135168                     // bias sums fp32: 3*1024*4
#define H64_OFF    147456                     // h bf16 u64[4 rep][32][256]: 256 KB (zeroed)
#define ZERO_BYTES (H64_OFF + 262144)
#define RH64_OFF   ZERO_BYTES                 // r*h u64[4 rep][32][256]: 256 KB (wbr)
#define XB_OFF     (1<<20)                    // x bf16: 8 MB
#define WB_OFF     (9<<20)                    // 6 weight mats bf16: 12 MB
#define WS_FULL    (21u<<20)
#define REP_STRIDE 8192                       // u64 per replica (64 KB)

__device__ __forceinline__ float bf2f(u16 v) {
    unsigned u = ((unsigned)v) << 16;
    return __builtin_bit_cast(float, u);
}
__device__ __forceinline__ u16 f2bf(float f) {
    unsigned u = __builtin_bit_cast(unsigned, f);
    unsigned r = 0x7fffu + ((u >> 16) & 1u);   // RNE
    return (u16)((u + r) >> 16);
}
__device__ __forceinline__ float sigm(float x) { return 1.0f / (1.0f + __expf(-x)); }

__device__ __forceinline__ short8 cvt8f(const float* f) {
    short8 r;
#pragma unroll
    for (int j = 0; j < 8; j++) r[j] = (short)f2bf(f[j]);
    return r;
}
__device__ __forceinline__ short8 cvt8any(const void* src, long ei, unsigned isbf) {
    if (isbf) return *(const short8*)((const u16*)src + ei);
    return cvt8f((const float*)src + ei);
}

union Q2 { u64 q[2]; short8 s; };
// Coherent (L2-bypassing, sc1) 16-byte fragment load as two relaxed agent atomics.
__device__ __forceinline__ short8 ld_coh8(const u64* p) {
    Q2 u;
    u.q[0] = __hip_atomic_load(p,     __ATOMIC_RELAXED, __HIP_MEMORY_SCOPE_AGENT);
    u.q[1] = __hip_atomic_load(p + 1, __ATOMIC_RELAXED, __HIP_MEMORY_SCOPE_AGENT);
    return u.s;
}
__device__ __forceinline__ u64 ld64(const u64* p) {
    return __hip_atomic_load(p, __ATOMIC_RELAXED, __HIP_MEMORY_SCOPE_AGENT);
}
__device__ __forceinline__ unsigned ld_flag(const unsigned* p) {
    return __hip_atomic_load(p, __ATOMIC_RELAXED, __HIP_MEMORY_SCOPE_AGENT);
}
__device__ __forceinline__ void st_flag(unsigned* p, unsigned v) {
    __hip_atomic_store(p, v, __ATOMIC_RELAXED, __HIP_MEMORY_SCOPE_AGENT);
}
__device__ __forceinline__ void st64(u64* p, u64 v) {
    __hip_atomic_store(p, v, __ATOMIC_RELAXED, __HIP_MEMORY_SCOPE_AGENT);
}

// ---- leaderless all-to-all grid barrier (R5, kept; now 64 participants) ----
// Each block stores a MONOTONE epoch to 4 replica lines of its own 1KB-strided
// flag page; threads 0..NB-1 each poll one block's flag, reading replica
// (blk&3). Ordering: data moves via sc1 atomics (coherent at L3);
// __syncthreads drains vmcnt so all data stores are visible BEFORE the flag
// stores issue; consumer loads are also sc1 so they cannot hit stale L2.
__device__ __forceinline__ void gbar(unsigned* flgs, unsigned e, unsigned nb) {
    __syncthreads();                 // drains vmcnt: all sc1 data stores at L3
    const unsigned tid = threadIdx.x;
    if (tid < 4)
        st_flag(flgs + blockIdx.x * 256 + tid * 64, e);   // 4 replicas, 256B apart
    if (tid < nb) {
        const unsigned* fp = flgs + tid * 256 + (blockIdx.x & 3) * 64;
        while (ld_flag(fp) < e)
            __builtin_amdgcn_s_sleep(1);
    }
    __syncthreads();
}

struct Ptrs { const void* p[13]; };

// dtype detector: bf16 u16s have exponent in [100,140] (or zero) ~100% for
// N(0,s) data; fp32 read as u16 passes ~58%.
__global__ __launch_bounds__(256) void detect_k(Ptrs ps, unsigned* flags) {
    const u16* a = (const u16*)ps.p[blockIdx.x];
    __shared__ int tot;
    if (threadIdx.x == 0) tot = 0;
    __syncthreads();
    int cnt = 0;
    for (int i = threadIdx.x; i < 1024; i += 256) {
        unsigned u = a[i];
        unsigned e = (u >> 7) & 0xFF;
        cnt += (e == 0 || (e >= 100 && e <= 140)) ? 1 : 0;
    }
    atomicAdd(&tot, cnt);
    __syncthreads();
    if (threadIdx.x == 0) flags[blockIdx.x] = (tot >= 920) ? 1u : 0u;
}

struct SPtrs { const void* x; const void* W[6]; const void* b[6]; };
// W order: Wz,Uz,Wr,Ur,Wh,Uh (flags 1,3,5,7,9,11); b pairs (bz,cz),(br,cr),(bh,ch).

__global__ __launch_bounds__(256) void stage_k(SPtrs ps, const unsigned* __restrict__ flags,
                                               u16* __restrict__ xb, u16* __restrict__ wb,
                                               float* __restrict__ bs, int do_x) {
    int blk = blockIdx.x, tid = threadIdx.x;
    int xblocks = do_x ? 2048 : 0;
    if (blk < xblocks) {                         // x: 4M elems
        long ei = ((long)blk * 256 + tid) * 8;
        *(short8*)(xb + ei) = cvt8any(ps.x, ei, flags[0]);
    } else if (blk < xblocks + 6 * 512) {        // weights: 1M elems each
        int r = (blk - xblocks) >> 9;
        const int fidx[6] = {1, 3, 5, 7, 9, 11};
        long ei = ((long)((blk - xblocks) & 511) * 256 + tid) * 8;
        *(short8*)(wb + (long)r * 1048576 + ei) = cvt8any(ps.W[r], ei, flags[fidx[r]]);
    } else {                                     // bias sums: bs[0]=z, [1]=r, [2]=h
        const int fb[3] = {2, 6, 10}, fc[3] = {4, 8, 12};
        for (int g = 0; g < 3; g++)
            for (int i = tid; i < 1024; i += 256) {
                float b = flags[fb[g]] ? bf2f(((const u16*)ps.b[2 * g])[i])
                                       : ((const float*)ps.b[2 * g])[i];
                float c = flags[fc[g]] ? bf2f(((const u16*)ps.b[2 * g + 1])[i])
                                       : ((const float*)ps.b[2 * g + 1])[i];
                bs[g * 1024 + i] = b + c;
            }
    }
}

// ---- persistent GRU: 64 blocks x 1024 thr (16 waves), 16x32 tiles ----
// R8 change (sc1 volume + fan-out): 64 blocks instead of 128; block
// (ct=blk>>1, rt=blk&1) owns rows R=[16rt,+16), cols C=[32ct,+32). Each wave
// keeps its K-split role but runs TWO col-subtile accumulators sharing one
// A-fragment. Total sc1 reads/step: h 4->2 MB, rh 4->2 MB; barrier
// participants 128->64 (single-wave poll). Protocol/ordering identical to R7.
__global__ __launch_bounds__(1024, 4) void gru_rec(
    const void* __restrict__ xbase, int xmode,   // 1: xbase bf16-staged; 0: raw x
    const u16* __restrict__ wb, const float* __restrict__ bs,
    u64* __restrict__ h64, u64* __restrict__ rh64,
    const unsigned* __restrict__ flags,
    unsigned* __restrict__ flgs,
    void* __restrict__ out)
{
    const int tid  = threadIdx.x;
    const int lane = tid & 63, wave = tid >> 6;      // wave 0..15
    const int quad = lane >> 4, ln = lane & 15;
    const int blk  = blockIdx.x;
    const unsigned NB = gridDim.x;                   // 64
    const int rep  = blk & 3;                        // data replica this block reads

    const unsigned xisbf = xmode ? 1u : flags[0];
    const unsigned outbf = flags[0];

    const int ct = blk >> 1, rt = blk & 1;
    const int R = rt * 16, C0 = ct * 32;

    // Phase A role: g = wave>>2 (0:hUr 1:xWr 2:hUz 3:xWz), kq = wave&3.
    const int gA  = wave >> 2, kqA = wave & 3;
    const int kb0 = kqA * 256;
    const int wmapA[4] = {3, 2, 1, 0};               // -> Ur, Wr, Uz, Wz
    const u16* BwA = wb + (long)wmapA[gA] * 1048576 + (C0 + ln) * 1024 + kb0 + quad * 8;
    const bool hA  = (gA == 0) || (gA == 2);
    const int hsc  = (kb0 >> 2) + quad * 2;          // hs u64 col base; iter i: +i*8
    const long xAo = ((long)(R + ln) * 128) * 1024 + kb0 + quad * 8; // + t*1024

    // Phase B role: gB = wave>>3 (0:rh@Uh 1:x@Wh), ke = wave&7.
    const int gB  = wave >> 3, keB = wave & 7;
    const int kb1 = keB * 128;
    const u16* BwB = wb + (long)(gB ? 4 : 5) * 1048576 + (C0 + ln) * 1024 + kb1 + quad * 8;
    const u64* rhq = rh64 + rep * REP_STRIDE + (R + ln) * 256 + (kb1 >> 2) + quad * 2; // +i*8
    const long xBo = ((long)(R + ln) * 128) * 1024 + kb1 + quad * 8; // + t*1024

    float bias_z[2], bias_r[2], bias_h[2];
#pragma unroll
    for (int s = 0; s < 2; s++) {
        bias_z[s] = bs[C0 + s * 16 + ln];
        bias_r[s] = bs[1024 + C0 + s * 16 + ln];
        bias_h[s] = bs[2048 + C0 + s * 16 + ln];
    }

    __shared__ float sA[16][2][4][64];  // per-wave partials x 2 col-subtiles (32 KB)
    __shared__ float zt[2][4][64];      // z tiles
    __shared__ float ht[2][4][64];      // h fp32 tiles (block-private)
    __shared__ u16   tT[2][16][20];     // transpose staging for u64 packing
    __shared__ u64   hs[16][258];       // staged h rows (R7 stride kept: 16B-aligned)

    if (wave < 2)
#pragma unroll
        for (int r = 0; r < 4; r++) ht[wave][r][lane] = 0.f;
    __syncthreads();

    const int prow = lane >> 2, pseg = lane & 3;     // packer geometry

    // staging source: wave w loads row R+w, lane l covers cols l, l+64, l+128, l+192
    const u64* hsrc = h64 + rep * REP_STRIDE + (R + wave) * 256 + lane;

    for (int t = 0; t < 128; t++) {
        { // ---- stage h rows into LDS (one sc1 read per word per block) ----
#pragma unroll
            for (int c = 0; c < 4; c++)
                hs[wave][lane + 64 * c] = ld64(hsrc + 64 * c);
        }
        __syncthreads();
        { // ---- phase A chains: 8 MFMAs x 2 col-subtiles (shared A-frag) ----
            f32x4 a0 = (f32x4){0.f, 0.f, 0.f, 0.f};
            f32x4 a1 = (f32x4){0.f, 0.f, 0.f, 0.f};
            const long xo = xAo + (long)t * 1024;
#pragma unroll
            for (int i = 0; i < 8; i++) {
                short8 a = hA ? *(const short8*)&hs[ln][hsc + i * 8]
                              : cvt8any(xbase, xo + i * 32, xisbf);
                a0 = __builtin_amdgcn_mfma_f32_16x16x32_bf16(
                    a, *(const short8*)(BwA + i * 32), a0, 0, 0, 0);
                a1 = __builtin_amdgcn_mfma_f32_16x16x32_bf16(
                    a, *(const short8*)(BwA + 16384 + i * 32), a1, 0, 0, 0);
            }
#pragma unroll
            for (int r = 0; r < 4; r++) {
                sA[wave][0][r][lane] = a0[r];
                sA[wave][1][r][lane] = a1[r];
            }
        }
        __syncthreads();
        if (wave < 2) {         // r reducers (sub = wave): r*h, publish 4 replicas
            const int s = wave;
#pragma unroll
            for (int r = 0; r < 4; r++) {
                float v = bias_r[s];
#pragma unroll
                for (int w = 0; w < 8; w++) v += sA[w][s][r][lane];
                float rv = sigm(v);
                tT[s][quad * 4 + r][ln] = f2bf(rv * ht[s][r][lane]);
            }
            u64 v = (u64)tT[s][prow][pseg * 4] | ((u64)tT[s][prow][pseg * 4 + 1] << 16)
                  | ((u64)tT[s][prow][pseg * 4 + 2] << 32) | ((u64)tT[s][prow][pseg * 4 + 3] << 48);
            u64* dst = &rh64[(R + prow) * 256 + ct * 8 + s * 4 + pseg];
#pragma unroll
            for (int rp = 0; rp < 4; rp++) st64(dst + rp * REP_STRIDE, v);
        } else if (wave < 4) {  // z reducers (sub = wave-2) -> LDS
            const int s = wave - 2;
#pragma unroll
            for (int r = 0; r < 4; r++) {
                float v = bias_z[s];
#pragma unroll
                for (int w = 8; w < 16; w++) v += sA[w][s][r][lane];
                zt[s][r][lane] = sigm(v);
            }
        }
        gbar(flgs, 2 * t + 1, NB);
        { // ---- phase B chains: 4 MFMAs x 2 col-subtiles ----
            f32x4 b0 = (f32x4){0.f, 0.f, 0.f, 0.f};
            f32x4 b1 = (f32x4){0.f, 0.f, 0.f, 0.f};
            const long xo = xBo + (long)t * 1024;
#pragma unroll
            for (int i = 0; i < 4; i++) {
                short8 a = (gB == 0) ? ld_coh8(rhq + i * 8)
                                     : cvt8any(xbase, xo + i * 32, xisbf);
                b0 = __builtin_amdgcn_mfma_f32_16x16x32_bf16(
                    a, *(const short8*)(BwB + i * 32), b0, 0, 0, 0);
                b1 = __builtin_amdgcn_mfma_f32_16x16x32_bf16(
                    a, *(const short8*)(BwB + 16384 + i * 32), b1, 0, 0, 0);
            }
#pragma unroll
            for (int r = 0; r < 4; r++) {
                sA[wave][0][r][lane] = b0[r];
                sA[wave][1][r][lane] = b1[r];
            }
        }
        __syncthreads();
        if (wave < 2) {         // combine (sub = wave): h' = (1-z)h + z*sigm(.)
            const int s = wave;
#pragma unroll
            for (int r = 0; r < 4; r++) {
                float v = bias_h[s];
#pragma unroll
                for (int w = 0; w < 16; w++) v += sA[w][s][r][lane];
                float hh = sigm(v);
                float z  = zt[s][r][lane];
                float hv = ht[s][r][lane];
                float hn = (1.0f - z) * hv + z * hh;
                ht[s][r][lane] = hn;
                u16 hb = f2bf(hn);
                int row = quad * 4 + r;
                tT[s][row][ln] = hb;
                long oi = ((long)(t * 32) + R + row) * 1024 + C0 + s * 16 + ln;  // ys (T,B,D)
                if (outbf) ((u16*)out)[oi] = hb;
                else       ((float*)out)[oi] = hn;
            }
            u64 v = (u64)tT[s][prow][pseg * 4] | ((u64)tT[s][prow][pseg * 4 + 1] << 16)
                  | ((u64)tT[s][prow][pseg * 4 + 2] << 32) | ((u64)tT[s][prow][pseg * 4 + 3] << 48);
            u64* dst = &h64[(R + prow) * 256 + ct * 8 + s * 4 + pseg];
#pragma unroll
            for (int rp = 0; rp < 4; rp++) st64(dst + rp * REP_STRIDE, v);
        }
        if (t < 127) gbar(flgs, 2 * t + 2, NB);
    }
}

extern "C" void kernel_launch(void* const* d_in, const int* in_sizes, int n_in,
                              void* d_out, int out_size, void* d_ws, size_t ws_size,
                              hipStream_t stream)
{
    char* ws = (char*)d_ws;
    hipMemsetAsync(d_ws, 0, ZERO_BYTES, stream);   // barrier flags + dtypes + h64 reps

    unsigned* flgs  = (unsigned*)(ws + CNT_OFF);
    unsigned* flags = (unsigned*)(ws + FLG_OFF);
    float*    bs    = (float*)(ws + BS_OFF);
    u64*      h64   = (u64*)(ws + H64_OFF);
    u64*      rh64  = (u64*)(ws + RH64_OFF);
    u16*      xb    = (u16*)(ws + XB_OFF);

    Ptrs dp;
    for (int i = 0; i < 13; i++) dp.p[i] = d_in[i];
    detect_k<<<13, 256, 0, stream>>>(dp, flags);

    SPtrs sp;
    sp.x = d_in[0];
    sp.W[0] = d_in[1];  sp.W[1] = d_in[3];   // Wz, Uz
    sp.W[2] = d_in[5];  sp.W[3] = d_in[7];   // Wr, Ur
    sp.W[4] = d_in[9];  sp.W[5] = d_in[11];  // Wh, Uh
    sp.b[0] = d_in[2];  sp.b[1] = d_in[4];   // bz, cz
    sp.b[2] = d_in[6];  sp.b[3] = d_in[8];   // br, cr
    sp.b[4] = d_in[10]; sp.b[5] = d_in[12];  // bh, ch

    if (ws_size >= WS_FULL) {
        u16* wbuf = (u16*)(ws + WB_OFF);
        stage_k<<<2048 + 6 * 512 + 1, 256, 0, stream>>>(sp, flags, xb, wbuf, bs, 1);
        gru_rec<<<64, 1024, 0, stream>>>(xb, 1, wbuf, bs, h64, rh64, flags, flgs, d_out);
    } else {
        u16* wbuf = (u16*)(ws + XB_OFF);     // no x staging; weights at 1 MB
        stage_k<<<6 * 512 + 1, 256, 0, stream>>>(sp, flags, xb, wbuf, bs, 0);
        gru_rec<<<64, 1024, 0, stream>>>(d_in[0], 0, wbuf, bs, h64, rh64, flags, flgs, d_out);
    }
}

// Round 9
// 1802.671 us; speedup vs baseline: 1.1520x; 1.1520x over previous
//
#include <hip/hip_runtime.h>
#include <stdint.h>

// B=32, T=128, DIN=DOUT=1024. Input dtypes detected at runtime (bf16 vs fp32).
typedef unsigned short u16;
typedef unsigned long long u64;
typedef __attribute__((ext_vector_type(8))) short short8;   // 8 x bf16 MFMA operand
typedef __attribute__((ext_vector_type(4))) float f32x4;    // MFMA accumulator
typedef __attribute__((ext_vector_type(4))) unsigned u32x4; // 16B coherent load payload

// ---- workspace layout (bytes) ----
// Anti-contention layout (R5, kept): barrier flags strided 1KB with 4 replicas
// 256B apart; h and r*h tile buffers replicated 4x.
// R9: flags split into 2 independent rt-domains of 64 pages each.
#define CNT_OFF    0                          // barrier flags: 2 x 64 x 1KB (zeroed)
#define FLG_OFF    131072                     // 13 dtype flags
#define BS_OFF     135168                     // bias sums fp32: 3*1024*4
#define H64_OFF    147456                     // h bf16 u64[4 rep][32][256]: 256 KB (zeroed)
#define ZERO_BYTES (H64_OFF + 262144)
#define RH64_OFF   ZERO_BYTES                 // r*h u64[4 rep][32][256]: 256 KB (wbr)
#define XB_OFF     (1<<20)                    // x bf16: 8 MB
#define WB_OFF     (9<<20)                    // 6 weight mats bf16: 12 MB
#define WS_FULL    (21u<<20)
#define REP_STRIDE 8192                       // u64 per replica (64 KB)

__device__ __forceinline__ float bf2f(u16 v) {
    unsigned u = ((unsigned)v) << 16;
    return __builtin_bit_cast(float, u);
}
__device__ __forceinline__ u16 f2bf(float f) {
    unsigned u = __builtin_bit_cast(unsigned, f);
    unsigned r = 0x7fffu + ((u >> 16) & 1u);   // RNE
    return (u16)((u + r) >> 16);
}
__device__ __forceinline__ float sigm(float x) { return 1.0f / (1.0f + __expf(-x)); }

__device__ __forceinline__ short8 cvt8f(const float* f) {
    short8 r;
#pragma unroll
    for (int j = 0; j < 8; j++) r[j] = (short)f2bf(f[j]);
    return r;
}
__device__ __forceinline__ short8 cvt8any(const void* src, long ei, unsigned isbf) {
    if (isbf) return *(const short8*)((const u16*)src + ei);
    return cvt8f((const float*)src + ei);
}

__device__ __forceinline__ unsigned ld_flag(const unsigned* p) {
    return __hip_atomic_load(p, __ATOMIC_RELAXED, __HIP_MEMORY_SCOPE_AGENT);
}
__device__ __forceinline__ void st_flag(unsigned* p, unsigned v) {
    __hip_atomic_store(p, v, __ATOMIC_RELAXED, __HIP_MEMORY_SCOPE_AGENT);
}
__device__ __forceinline__ void st64(u64* p, u64 v) {
    __hip_atomic_store(p, v, __ATOMIC_RELAXED, __HIP_MEMORY_SCOPE_AGENT);
}

// ---- 16-byte coherent loads (R9) ----
// We need L2-bypassing (sc1) coherent reads, NOT atomicity: a 16B dwordx4
// with sc0 sc1 is ONE sc1 transaction where two 8B atomic loads were two.
// Batched issue + single vmcnt(0) keeps the loads pipelined.
__device__ __forceinline__ void ld2_coh16(u32x4* d0, u32x4* d1,
                                          const u64* p0, const u64* p1) {
    asm volatile(
        "global_load_dwordx4 %0, %2, off sc0 sc1\n\t"
        "global_load_dwordx4 %1, %3, off sc0 sc1\n\t"
        "s_waitcnt vmcnt(0)"
        : "=&v"(*d0), "=&v"(*d1)
        : "v"(p0), "v"(p1)
        : "memory");
}
__device__ __forceinline__ void ld4_coh16(u32x4* d0, u32x4* d1, u32x4* d2, u32x4* d3,
                                          const u64* p) {
    asm volatile(
        "global_load_dwordx4 %0, %4, off sc0 sc1\n\t"
        "global_load_dwordx4 %1, %5, off sc0 sc1\n\t"
        "global_load_dwordx4 %2, %6, off sc0 sc1\n\t"
        "global_load_dwordx4 %3, %7, off sc0 sc1\n\t"
        "s_waitcnt vmcnt(0)"
        : "=&v"(*d0), "=&v"(*d1), "=&v"(*d2), "=&v"(*d3)
        : "v"(p), "v"(p + 8), "v"(p + 16), "v"(p + 24)
        : "memory");
}

// ---- leaderless all-to-all barrier, per-rt domain (R9) ----
// The rt=0 and rt=1 row-groups never read each other's h/rh (each block only
// touches its own rt's rows) -> the global barrier over-synchronized. Each
// domain: 64 blocks, own 64KB flag region. Protocol otherwise identical to
// R5/R7: monotone epoch to 4 replica lines of own 1KB page; 64 pollers read
// replica (ct&3). __syncthreads drains vmcnt before flag stores.
__device__ __forceinline__ void gbar(unsigned* myflgs, unsigned e, int ct) {
    __syncthreads();                 // drains vmcnt: all sc1 data stores at L3
    const unsigned tid = threadIdx.x;
    if (tid < 4)
        st_flag(myflgs + ct * 256 + tid * 64, e);   // 4 replicas, 256B apart
    if (tid < 64) {
        const unsigned* fp = myflgs + tid * 256 + (ct & 3) * 64;
        while (ld_flag(fp) < e)
            __builtin_amdgcn_s_sleep(1);
    }
    __syncthreads();
}

struct Ptrs { const void* p[13]; };

// dtype detector: bf16 u16s have exponent in [100,140] (or zero) ~100% for
// N(0,s) data; fp32 read as u16 passes ~58%.
__global__ __launch_bounds__(256) void detect_k(Ptrs ps, unsigned* flags) {
    const u16* a = (const u16*)ps.p[blockIdx.x];
    __shared__ int tot;
    if (threadIdx.x == 0) tot = 0;
    __syncthreads();
    int cnt = 0;
    for (int i = threadIdx.x; i < 1024; i += 256) {
        unsigned u = a[i];
        unsigned e = (u >> 7) & 0xFF;
        cnt += (e == 0 || (e >= 100 && e <= 140)) ? 1 : 0;
    }
    atomicAdd(&tot, cnt);
    __syncthreads();
    if (threadIdx.x == 0) flags[blockIdx.x] = (tot >= 920) ? 1u : 0u;
}

struct SPtrs { const void* x; const void* W[6]; const void* b[6]; };
// W order: Wz,Uz,Wr,Ur,Wh,Uh (flags 1,3,5,7,9,11); b pairs (bz,cz),(br,cr),(bh,ch).

__global__ __launch_bounds__(256) void stage_k(SPtrs ps, const unsigned* __restrict__ flags,
                                               u16* __restrict__ xb, u16* __restrict__ wb,
                                               float* __restrict__ bs, int do_x) {
    int blk = blockIdx.x, tid = threadIdx.x;
    int xblocks = do_x ? 2048 : 0;
    if (blk < xblocks) {                         // x: 4M elems
        long ei = ((long)blk * 256 + tid) * 8;
        *(short8*)(xb + ei) = cvt8any(ps.x, ei, flags[0]);
    } else if (blk < xblocks + 6 * 512) {        // weights: 1M elems each
        int r = (blk - xblocks) >> 9;
        const int fidx[6] = {1, 3, 5, 7, 9, 11};
        long ei = ((long)((blk - xblocks) & 511) * 256 + tid) * 8;
        *(short8*)(wb + (long)r * 1048576 + ei) = cvt8any(ps.W[r], ei, flags[fidx[r]]);
    } else {                                     // bias sums: bs[0]=z, [1]=r, [2]=h
        const int fb[3] = {2, 6, 10}, fc[3] = {4, 8, 12};
        for (int g = 0; g < 3; g++)
            for (int i = tid; i < 1024; i += 256) {
                float b = flags[fb[g]] ? bf2f(((const u16*)ps.b[2 * g])[i])
                                       : ((const float*)ps.b[2 * g])[i];
                float c = flags[fc[g]] ? bf2f(((const u16*)ps.b[2 * g + 1])[i])
                                       : ((const float*)ps.b[2 * g + 1])[i];
                bs[g * 1024 + i] = b + c;
            }
    }
}

// ---- persistent GRU: 128 blocks x 1024 thr (16 waves), K-split chains ----
// Block (ct=blk>>1, rt=blk&1) owns rows R=[16rt,+16) (batch), cols C=[16ct,+16).
// h and r*h live as u64[4 replicas][32][256] (4 bf16 per u64), accessed ONLY
// via sc1 ops (L3 coherence point). R7 structure (best: 1328us) with R9's
// 16B coherent loads and per-rt barrier domains.
__global__ __launch_bounds__(1024, 4) void gru_rec(
    const void* __restrict__ xbase, int xmode,   // 1: xbase bf16-staged; 0: raw x
    const u16* __restrict__ wb, const float* __restrict__ bs,
    u64* __restrict__ h64, u64* __restrict__ rh64,
    const unsigned* __restrict__ flags,
    unsigned* __restrict__ flgs,
    void* __restrict__ out)
{
    const int tid  = threadIdx.x;
    const int lane = tid & 63, wave = tid >> 6;      // wave 0..15
    const int quad = lane >> 4, ln = lane & 15;
    const int blk  = blockIdx.x;
    const int rep  = blk & 3;                        // data replica this block reads

    const unsigned xisbf = xmode ? 1u : flags[0];
    const unsigned outbf = flags[0];

    const int ct = blk >> 1, rt = blk & 1;
    const int R = rt * 16, C0 = ct * 16;
    unsigned* myflgs = flgs + rt * 16384;            // per-rt 64KB flag domain

    // Phase A role: g = wave>>2 (0:hUr 1:xWr 2:hUz 3:xWz), kq = wave&3.
    const int gA  = wave >> 2, kqA = wave & 3;
    const int kb0 = kqA * 256;
    const int wmapA[4] = {3, 2, 1, 0};               // -> Ur, Wr, Uz, Wz
    const u16* BwA = wb + (long)wmapA[gA] * 1048576 + (C0 + ln) * 1024 + kb0 + quad * 8;
    const bool hA  = (gA == 0) || (gA == 2);
    const int hsc  = (kb0 >> 2) + quad * 2;          // hs u64 col base; iter i: +i*8
    const long xAo = ((long)(R + ln) * 128) * 1024 + kb0 + quad * 8; // + t*1024

    // Phase B role: gB = wave>>3 (0:rh@Uh 1:x@Wh), ke = wave&7.
    const int gB  = wave >> 3, keB = wave & 7;
    const int kb1 = keB * 128;
    const u16* BwB = wb + (long)(gB ? 4 : 5) * 1048576 + (C0 + ln) * 1024 + kb1 + quad * 8;
    const u64* rhq = rh64 + rep * REP_STRIDE + (R + ln) * 256 + (kb1 >> 2) + quad * 2; // +i*8
    const long xBo = ((long)(R + ln) * 128) * 1024 + kb1 + quad * 8; // + t*1024

    const float bias_z = bs[C0 + ln];
    const float bias_r = bs[1024 + C0 + ln];
    const float bias_h = bs[2048 + C0 + ln];

    __shared__ float sA[16][4][64];    // per-wave partials, conflict-free layout
    __shared__ float zt[4][64];        // z tile
    __shared__ float ht[4][64];        // h fp32 tile (block-private)
    __shared__ u16   tT[16][20];       // transpose staging for u64 packing
    __shared__ __align__(16) u64 hs[16][258];  // staged h rows (row stride even ->
                                               // every 16B chunk stays aligned)

    if (wave == 0)
#pragma unroll
        for (int r = 0; r < 4; r++) ht[r][lane] = 0.f;
    __syncthreads();

    const int prow = lane >> 2, pseg = lane & 3;     // packer geometry (wave 0)

    // staging source: wave w stages row R+w; lane l covers 16B chunks at
    // u64 cols [2l, 2l+1] and [128+2l, 128+2l+1]
    const u64* hsrc = h64 + rep * REP_STRIDE + (R + wave) * 256 + 2 * lane;

    for (int t = 0; t < 128; t++) {
        { // ---- stage h rows into LDS: 2 x 16B coherent loads per lane ----
            u32x4 d0, d1;
            ld2_coh16(&d0, &d1, hsrc, hsrc + 128);
            *(u32x4*)&hs[wave][2 * lane]       = d0;
            *(u32x4*)&hs[wave][128 + 2 * lane] = d1;
        }
        __syncthreads();
        { // ---- phase A chains: 8 MFMAs ----
            f32x4 acc = (f32x4){0.f, 0.f, 0.f, 0.f};
            const long xo = xAo + (long)t * 1024;
#pragma unroll
            for (int i = 0; i < 8; i++) {
                short8 a = hA ? *(const short8*)&hs[ln][hsc + i * 8]
                              : cvt8any(xbase, xo + i * 32, xisbf);
                acc = __builtin_amdgcn_mfma_f32_16x16x32_bf16(
                    a, *(const short8*)(BwA + i * 32), acc, 0, 0, 0);
            }
#pragma unroll
            for (int r = 0; r < 4; r++) sA[wave][r][lane] = acc[r];
        }
        __syncthreads();
        if (wave == 0) {        // r -> r*h, transpose via LDS, publish 4 replicas
#pragma unroll
            for (int r = 0; r < 4; r++) {
                float s = bias_r;
#pragma unroll
                for (int w = 0; w < 8; w++) s += sA[w][r][lane];
                float rv = sigm(s);
                tT[quad * 4 + r][ln] = f2bf(rv * ht[r][lane]);
            }
            u64 v = (u64)tT[prow][pseg * 4] | ((u64)tT[prow][pseg * 4 + 1] << 16)
                  | ((u64)tT[prow][pseg * 4 + 2] << 32) | ((u64)tT[prow][pseg * 4 + 3] << 48);
            u64* dst = &rh64[(R + prow) * 256 + ct * 4 + pseg];
#pragma unroll
            for (int rp = 0; rp < 4; rp++) st64(dst + rp * REP_STRIDE, v);
        } else if (wave == 1) { // z -> LDS
#pragma unroll
            for (int r = 0; r < 4; r++) {
                float s = bias_z;
#pragma unroll
                for (int w = 8; w < 16; w++) s += sA[w][r][lane];
                zt[r][lane] = sigm(s);
            }
        }
        gbar(myflgs, 2 * t + 1, ct);
        { // ---- phase B chains: 4 MFMAs (rh via 4 x 16B coherent loads) ----
            f32x4 acc = (f32x4){0.f, 0.f, 0.f, 0.f};
            if (gB == 0) {
                u32x4 m0, m1, m2, m3;
                ld4_coh16(&m0, &m1, &m2, &m3, rhq);
                acc = __builtin_amdgcn_mfma_f32_16x16x32_bf16(
                    __builtin_bit_cast(short8, m0), *(const short8*)(BwB +  0), acc, 0, 0, 0);
                acc = __builtin_amdgcn_mfma_f32_16x16x32_bf16(
                    __builtin_bit_cast(short8, m1), *(const short8*)(BwB + 32), acc, 0, 0, 0);
                acc = __builtin_amdgcn_mfma_f32_16x16x32_bf16(
                    __builtin_bit_cast(short8, m2), *(const short8*)(BwB + 64), acc, 0, 0, 0);
                acc = __builtin_amdgcn_mfma_f32_16x16x32_bf16(
                    __builtin_bit_cast(short8, m3), *(const short8*)(BwB + 96), acc, 0, 0, 0);
            } else {
                const long xo = xBo + (long)t * 1024;
#pragma unroll
                for (int i = 0; i < 4; i++) {
                    short8 a = cvt8any(xbase, xo + i * 32, xisbf);
                    acc = __builtin_amdgcn_mfma_f32_16x16x32_bf16(
                        a, *(const short8*)(BwB + i * 32), acc, 0, 0, 0);
                }
            }
#pragma unroll
            for (int r = 0; r < 4; r++) sA[wave][r][lane] = acc[r];
        }
        __syncthreads();
        if (wave == 0) {        // combine: h' = (1-z)h + z*sigm(.), publish h x4
#pragma unroll
            for (int r = 0; r < 4; r++) {
                float s = bias_h;
#pragma unroll
                for (int w = 0; w < 16; w++) s += sA[w][r][lane];
                float hh = sigm(s);
                float z  = zt[r][lane];
                float hv = ht[r][lane];
                float hn = (1.0f - z) * hv + z * hh;
                ht[r][lane] = hn;
                u16 hb = f2bf(hn);
                int row = quad * 4 + r;
                tT[row][ln] = hb;
                long oi = ((long)(t * 32) + R + row) * 1024 + C0 + ln;  // ys (T,B,D)
                if (outbf) ((u16*)out)[oi] = hb;
                else       ((float*)out)[oi] = hn;
            }
            u64 v = (u64)tT[prow][pseg * 4] | ((u64)tT[prow][pseg * 4 + 1] << 16)
                  | ((u64)tT[prow][pseg * 4 + 2] << 32) | ((u64)tT[prow][pseg * 4 + 3] << 48);
            u64* dst = &h64[(R + prow) * 256 + ct * 4 + pseg];
#pragma unroll
            for (int rp = 0; rp < 4; rp++) st64(dst + rp * REP_STRIDE, v);
        }
        if (t < 127) gbar(myflgs, 2 * t + 2, ct);
    }
}

extern "C" void kernel_launch(void* const* d_in, const int* in_sizes, int n_in,
                              void* d_out, int out_size, void* d_ws, size_t ws_size,
                              hipStream_t stream)
{
    char* ws = (char*)d_ws;
    hipMemsetAsync(d_ws, 0, ZERO_BYTES, stream);   // barrier flags + dtypes + h64 reps

    unsigned* flgs  = (unsigned*)(ws + CNT_OFF);
    unsigned* flags = (unsigned*)(ws + FLG_OFF);
    float*    bs    = (float*)(ws + BS_OFF);
    u64*      h64   = (u64*)(ws + H64_OFF);
    u64*      rh64  = (u64*)(ws + RH64_OFF);
    u16*      xb    = (u16*)(ws + XB_OFF);

    Ptrs dp;
    for (int i = 0; i < 13; i++) dp.p[i] = d_in[i];
    detect_k<<<13, 256, 0, stream>>>(dp, flags);

    SPtrs sp;
    sp.x = d_in[0];
    sp.W[0] = d_in[1];  sp.W[1] = d_in[3];   // Wz, Uz
    sp.W[2] = d_in[5];  sp.W[3] = d_in[7];   // Wr, Ur
    sp.W[4] = d_in[9];  sp.W[5] = d_in[11];  // Wh, Uh
    sp.b[0] = d_in[2];  sp.b[1] = d_in[4];   // bz, cz
    sp.b[2] = d_in[6];  sp.b[3] = d_in[8];   // br, cr
    sp.b[4] = d_in[10]; sp.b[5] = d_in[12];  // bh, ch

    if (ws_size >= WS_FULL) {
        u16* wbuf = (u16*)(ws + WB_OFF);
        stage_k<<<2048 + 6 * 512 + 1, 256, 0, stream>>>(sp, flags, xb, wbuf, bs, 1);
        gru_rec<<<128, 1024, 0, stream>>>(xb, 1, wbuf, bs, h64, rh64, flags, flgs, d_out);
    } else {
        u16* wbuf = (u16*)(ws + XB_OFF);     // no x staging; weights at 1 MB
        stage_k<<<6 * 512 + 1, 256, 0, stream>>>(sp, flags, xb, wbuf, bs, 0);
        gru_rec<<<128, 1024, 0, stream>>>(d_in[0], 0, wbuf, bs, h64, rh64, flags, flgs, d_out);
    }
}

// Round 10
// 1686.442 us; speedup vs baseline: 1.2313x; 1.0689x over previous
//
#include <hip/hip_runtime.h>
#include <stdint.h>

// B=32, T=128, DIN=DOUT=1024. Input dtypes detected at runtime (bf16 vs fp32).
typedef unsigned short u16;
typedef unsigned long long u64;
typedef __attribute__((ext_vector_type(8))) short short8;   // 8 x bf16 MFMA operand
typedef __attribute__((ext_vector_type(4))) float f32x4;    // MFMA accumulator

// ---- workspace layout (bytes) ----
// Anti-contention layout (R5, kept): barrier flags strided 1KB with 4 replicas
// 256B apart; h and r*h tile buffers replicated 4x.
// R10: flags split into 2 independent rt-domains of 64 pages each.
#define CNT_OFF    0                          // barrier flags: 2 x 64 x 1KB (zeroed)
#define FLG_OFF    131072                     // 13 dtype flags
#define BS_OFF     135168                     // bias sums fp32: 3*1024*4
#define H64_OFF    147456                     // h bf16 u64[4 rep][32][256]: 256 KB (zeroed)
#define ZERO_BYTES (H64_OFF + 262144)
#define RH64_OFF   ZERO_BYTES                 // r*h u64[4 rep][32][256]: 256 KB (wbr)
#define XB_OFF     (1<<20)                    // x bf16: 8 MB
#define WB_OFF     (9<<20)                    // 6 weight mats bf16: 12 MB
#define WS_FULL    (21u<<20)
#define REP_STRIDE 8192                       // u64 per replica (64 KB)

__device__ __forceinline__ float bf2f(u16 v) {
    unsigned u = ((unsigned)v) << 16;
    return __builtin_bit_cast(float, u);
}
__device__ __forceinline__ u16 f2bf(float f) {
    unsigned u = __builtin_bit_cast(unsigned, f);
    unsigned r = 0x7fffu + ((u >> 16) & 1u);   // RNE
    return (u16)((u + r) >> 16);
}
__device__ __forceinline__ float sigm(float x) { return 1.0f / (1.0f + __expf(-x)); }

__device__ __forceinline__ short8 cvt8f(const float* f) {
    short8 r;
#pragma unroll
    for (int j = 0; j < 8; j++) r[j] = (short)f2bf(f[j]);
    return r;
}
__device__ __forceinline__ short8 cvt8any(const void* src, long ei, unsigned isbf) {
    if (isbf) return *(const short8*)((const u16*)src + ei);
    return cvt8f((const float*)src + ei);
}

union Q2 { u64 q[2]; short8 s; };
// Coherent (L2-bypassing, sc1) 16-byte fragment load as two relaxed agent atomics.
// (R9's 16B asm loads regressed -33%: reverted to the proven path.)
__device__ __forceinline__ short8 ld_coh8(const u64* p) {
    Q2 u;
    u.q[0] = __hip_atomic_load(p,     __ATOMIC_RELAXED, __HIP_MEMORY_SCOPE_AGENT);
    u.q[1] = __hip_atomic_load(p + 1, __ATOMIC_RELAXED, __HIP_MEMORY_SCOPE_AGENT);
    return u.s;
}
__device__ __forceinline__ u64 ld64(const u64* p) {
    return __hip_atomic_load(p, __ATOMIC_RELAXED, __HIP_MEMORY_SCOPE_AGENT);
}
__device__ __forceinline__ unsigned ld_flag(const unsigned* p) {
    return __hip_atomic_load(p, __ATOMIC_RELAXED, __HIP_MEMORY_SCOPE_AGENT);
}
__device__ __forceinline__ void st_flag(unsigned* p, unsigned v) {
    __hip_atomic_store(p, v, __ATOMIC_RELAXED, __HIP_MEMORY_SCOPE_AGENT);
}
__device__ __forceinline__ void st64(u64* p, u64 v) {
    __hip_atomic_store(p, v, __ATOMIC_RELAXED, __HIP_MEMORY_SCOPE_AGENT);
}

struct Ptrs { const void* p[13]; };

// dtype detector: bf16 u16s have exponent in [100,140] (or zero) ~100% for
// N(0,s) data; fp32 read as u16 passes ~58%.
__global__ __launch_bounds__(256) void detect_k(Ptrs ps, unsigned* flags) {
    const u16* a = (const u16*)ps.p[blockIdx.x];
    __shared__ int tot;
    if (threadIdx.x == 0) tot = 0;
    __syncthreads();
    int cnt = 0;
    for (int i = threadIdx.x; i < 1024; i += 256) {
        unsigned u = a[i];
        unsigned e = (u >> 7) & 0xFF;
        cnt += (e == 0 || (e >= 100 && e <= 140)) ? 1 : 0;
    }
    atomicAdd(&tot, cnt);
    __syncthreads();
    if (threadIdx.x == 0) flags[blockIdx.x] = (tot >= 920) ? 1u : 0u;
}

struct SPtrs { const void* x; const void* W[6]; const void* b[6]; };
// W order: Wz,Uz,Wr,Ur,Wh,Uh (flags 1,3,5,7,9,11); b pairs (bz,cz),(br,cr),(bh,ch).

__global__ __launch_bounds__(256) void stage_k(SPtrs ps, const unsigned* __restrict__ flags,
                                               u16* __restrict__ xb, u16* __restrict__ wb,
                                               float* __restrict__ bs, int do_x) {
    int blk = blockIdx.x, tid = threadIdx.x;
    int xblocks = do_x ? 2048 : 0;
    if (blk < xblocks) {                         // x: 4M elems
        long ei = ((long)blk * 256 + tid) * 8;
        *(short8*)(xb + ei) = cvt8any(ps.x, ei, flags[0]);
    } else if (blk < xblocks + 6 * 512) {        // weights: 1M elems each
        int r = (blk - xblocks) >> 9;
        const int fidx[6] = {1, 3, 5, 7, 9, 11};
        long ei = ((long)((blk - xblocks) & 511) * 256 + tid) * 8;
        *(short8*)(wb + (long)r * 1048576 + ei) = cvt8any(ps.W[r], ei, flags[fidx[r]]);
    } else {                                     // bias sums: bs[0]=z, [1]=r, [2]=h
        const int fb[3] = {2, 6, 10}, fc[3] = {4, 8, 12};
        for (int g = 0; g < 3; g++)
            for (int i = tid; i < 1024; i += 256) {
                float b = flags[fb[g]] ? bf2f(((const u16*)ps.b[2 * g])[i])
                                       : ((const float*)ps.b[2 * g])[i];
                float c = flags[fc[g]] ? bf2f(((const u16*)ps.b[2 * g + 1])[i])
                                       : ((const float*)ps.b[2 * g + 1])[i];
                bs[g * 1024 + i] = b + c;
            }
    }
}

// ---- persistent GRU: 128 blocks x 1024 thr (16 waves), K-split chains ----
// Block (ct=blk>>1, rt=blk&1) owns rows R=[16rt,+16) (batch), cols C=[16ct,+16).
// h and r*h live as u64[4 replicas][32][256] (4 bf16 per u64), accessed ONLY
// via sc1 atomics (L3 coherence point). Data path = R7 (best, 1328us).
//
// R10: LEAN ROUNDS. Per half-step the old flow was
//   MFMA -> sync -> publish -> gbar{sync, flag, poll, sync}     (3 syncs)
// The new round primitive is
//   MFMA -> sync -> {w0: publish + OWN vmcnt(0) + flag | w1: other gate's
//   reduce / out stores | w15: poll 64 producer flags} -> sync  (2 syncs)
// - flag issues right after wave0's wave-local drain (no block rendezvous
//   first) -> each round's flag goes out earlier.
// - wave15's 64 lanes poll the 64 same-rt producer pages (1 flag/lane)
//   concurrently with wave0's publish; the trailing sync is the gate.
// - out stores moved to wave 1 (duplicate h' compute) -> wave0's drain no
//   longer waits on 64 scattered u16 stores. ht is parity-double-buffered
//   to make wave0-write/wave1-read race-free.
// - flags split per-rt (rt groups share no h/rh data: dependence-preserving).
// WAR/RAW inheritance from R7: flag 2t+1 still implies "this block finished
// staging h(t) and phase A"; flag 2t+2 still implies "finished phase B reads
// of rh(t)". The transitive arguments are unchanged.
__global__ __launch_bounds__(1024, 4) void gru_rec(
    const void* __restrict__ xbase, int xmode,   // 1: xbase bf16-staged; 0: raw x
    const u16* __restrict__ wb, const float* __restrict__ bs,
    u64* __restrict__ h64, u64* __restrict__ rh64,
    const unsigned* __restrict__ flags,
    unsigned* __restrict__ flgs,
    void* __restrict__ out)
{
    const int tid  = threadIdx.x;
    const int lane = tid & 63, wave = tid >> 6;      // wave 0..15
    const int quad = lane >> 4, ln = lane & 15;
    const int blk  = blockIdx.x;
    const int rep  = blk & 3;                        // data replica this block reads

    const unsigned xisbf = xmode ? 1u : flags[0];
    const unsigned outbf = flags[0];

    const int ct = blk >> 1, rt = blk & 1;
    const int R = rt * 16, C0 = ct * 16;
    unsigned* myflgs = flgs + rt * 16384;            // per-rt 64KB flag domain

    // Phase A role: g = wave>>2 (0:hUr 1:xWr 2:hUz 3:xWz), kq = wave&3.
    const int gA  = wave >> 2, kqA = wave & 3;
    const int kb0 = kqA * 256;
    const int wmapA[4] = {3, 2, 1, 0};               // -> Ur, Wr, Uz, Wz
    const u16* BwA = wb + (long)wmapA[gA] * 1048576 + (C0 + ln) * 1024 + kb0 + quad * 8;
    const bool hA  = (gA == 0) || (gA == 2);
    const int hsc  = (kb0 >> 2) + quad * 2;          // hs u64 col base; iter i: +i*8
    const long xAo = ((long)(R + ln) * 128) * 1024 + kb0 + quad * 8; // + t*1024

    // Phase B role: gB = wave>>3 (0:rh@Uh 1:x@Wh), ke = wave&7.
    const int gB  = wave >> 3, keB = wave & 7;
    const int kb1 = keB * 128;
    const u16* BwB = wb + (long)(gB ? 4 : 5) * 1048576 + (C0 + ln) * 1024 + kb1 + quad * 8;
    const u64* rhq = rh64 + rep * REP_STRIDE + (R + ln) * 256 + (kb1 >> 2) + quad * 2; // +i*8
    const long xBo = ((long)(R + ln) * 128) * 1024 + kb1 + quad * 8; // + t*1024

    const float bias_z = bs[C0 + ln];
    const float bias_r = bs[1024 + C0 + ln];
    const float bias_h = bs[2048 + C0 + ln];

    __shared__ float sA[16][4][64];    // per-wave partials, conflict-free layout
    __shared__ float zt[4][64];        // z tile
    __shared__ float ht[2][4][64];     // h fp32 tile, parity double-buffered (R10)
    __shared__ u16   tT[16][20];       // transpose staging for u64 packing (wave0 only)
    __shared__ __align__(16) u64 hs[16][258];  // staged h rows (+2 pad, even stride)

    if (wave == 0)
#pragma unroll
        for (int r = 0; r < 4; r++) ht[0][r][lane] = 0.f;
    __syncthreads();

    const int prow = lane >> 2, pseg = lane & 3;     // packer geometry (wave 0)

    // staging source: wave w loads row R+w, lane l covers cols l, l+64, l+128, l+192
    const u64* hsrc = h64 + rep * REP_STRIDE + (R + wave) * 256 + lane;
    // wave15 poll pointer: lane l watches producer block (ct'=l) of my rt domain
    const unsigned* pollp = myflgs + lane * 256 + (ct & 3) * 64;

    for (int t = 0; t < 128; t++) {
        const int par = t & 1;                       // ht[par] = h(t) fp32
        { // ---- stage h rows into LDS (one sc1 read per word per block) ----
#pragma unroll
            for (int c = 0; c < 4; c++)
                hs[wave][lane + 64 * c] = ld64(hsrc + 64 * c);
        }
        __syncthreads();                             // (C) hs ready
        { // ---- phase A chains: 8 MFMAs ----
            f32x4 acc = (f32x4){0.f, 0.f, 0.f, 0.f};
            const long xo = xAo + (long)t * 1024;
#pragma unroll
            for (int i = 0; i < 8; i++) {
                short8 a = hA ? *(const short8*)&hs[ln][hsc + i * 8]
                              : cvt8any(xbase, xo + i * 32, xisbf);
                acc = __builtin_amdgcn_mfma_f32_16x16x32_bf16(
                    a, *(const short8*)(BwA + i * 32), acc, 0, 0, 0);
            }
#pragma unroll
            for (int r = 0; r < 4; r++) sA[wave][r][lane] = acc[r];
        }
        __syncthreads();                             // (A) sA ready
        // ---- mid round: publish rh | z-reduce | poll, then gate ----
        if (wave == 0) {        // r -> r*h, pack, publish 4 reps, drain, flag
#pragma unroll
            for (int r = 0; r < 4; r++) {
                float s = bias_r;
#pragma unroll
                for (int w = 0; w < 8; w++) s += sA[w][r][lane];
                float rv = sigm(s);
                tT[quad * 4 + r][ln] = f2bf(rv * ht[par][r][lane]);
            }
            u64 v = (u64)tT[prow][pseg * 4] | ((u64)tT[prow][pseg * 4 + 1] << 16)
                  | ((u64)tT[prow][pseg * 4 + 2] << 32) | ((u64)tT[prow][pseg * 4 + 3] << 48);
            u64* dst = &rh64[(R + prow) * 256 + ct * 4 + pseg];
#pragma unroll
            for (int rp = 0; rp < 4; rp++) st64(dst + rp * REP_STRIDE, v);
            asm volatile("s_waitcnt vmcnt(0)" ::: "memory");   // wave-local drain
            if (lane < 4) st_flag(myflgs + ct * 256 + lane * 64, 2 * t + 1);
        } else if (wave == 1) { // z -> LDS
#pragma unroll
            for (int r = 0; r < 4; r++) {
                float s = bias_z;
#pragma unroll
                for (int w = 8; w < 16; w++) s += sA[w][r][lane];
                zt[r][lane] = sigm(s);
            }
        } else if (wave == 15) { // poll all 64 same-rt producers
            while (ld_flag(pollp) < (unsigned)(2 * t + 1))
                __builtin_amdgcn_s_sleep(1);
        }
        __syncthreads();                             // (B) gate: rh(t) visible
        { // ---- phase B chains: 4 MFMAs ----
            f32x4 acc = (f32x4){0.f, 0.f, 0.f, 0.f};
            const long xo = xBo + (long)t * 1024;
#pragma unroll
            for (int i = 0; i < 4; i++) {
                short8 a = (gB == 0) ? ld_coh8(rhq + i * 8)
                                     : cvt8any(xbase, xo + i * 32, xisbf);
                acc = __builtin_amdgcn_mfma_f32_16x16x32_bf16(
                    a, *(const short8*)(BwB + i * 32), acc, 0, 0, 0);
            }
#pragma unroll
            for (int r = 0; r < 4; r++) sA[wave][r][lane] = acc[r];
        }
        __syncthreads();                             // (D) sB ready
        // ---- end round: publish h | out stores (dup compute) | poll, gate ----
        if (wave == 0) {        // h' = (1-z)h + z*sigm(.), pack, publish, flag
#pragma unroll
            for (int r = 0; r < 4; r++) {
                float s = bias_h;
#pragma unroll
                for (int w = 0; w < 16; w++) s += sA[w][r][lane];
                float hh = sigm(s);
                float z  = zt[r][lane];
                float hv = ht[par][r][lane];
                float hn = (1.0f - z) * hv + z * hh;
                ht[par ^ 1][r][lane] = hn;
                tT[quad * 4 + r][ln] = f2bf(hn);
            }
            u64 v = (u64)tT[prow][pseg * 4] | ((u64)tT[prow][pseg * 4 + 1] << 16)
                  | ((u64)tT[prow][pseg * 4 + 2] << 32) | ((u64)tT[prow][pseg * 4 + 3] << 48);
            u64* dst = &h64[(R + prow) * 256 + ct * 4 + pseg];
#pragma unroll
            for (int rp = 0; rp < 4; rp++) st64(dst + rp * REP_STRIDE, v);
            asm volatile("s_waitcnt vmcnt(0)" ::: "memory");   // wave-local drain
            if (lane < 4) st_flag(myflgs + ct * 256 + lane * 64, 2 * t + 2);
        } else if (wave == 1) { // duplicate h' compute; owns the out stores
#pragma unroll
            for (int r = 0; r < 4; r++) {
                float s = bias_h;
#pragma unroll
                for (int w = 0; w < 16; w++) s += sA[w][r][lane];
                float hh = sigm(s);
                float z  = zt[r][lane];
                float hv = ht[par][r][lane];
                float hn = (1.0f - z) * hv + z * hh;
                int row = quad * 4 + r;
                long oi = ((long)(t * 32) + R + row) * 1024 + C0 + ln;  // ys (T,B,D)
                if (outbf) ((u16*)out)[oi] = f2bf(hn);
                else       ((float*)out)[oi] = hn;
            }
        } else if (wave == 15) {
            if (t < 127)
                while (ld_flag(pollp) < (unsigned)(2 * t + 2))
                    __builtin_amdgcn_s_sleep(1);
        }
        __syncthreads();                             // (E) gate: h(t+1) visible
    }
}

extern "C" void kernel_launch(void* const* d_in, const int* in_sizes, int n_in,
                              void* d_out, int out_size, void* d_ws, size_t ws_size,
                              hipStream_t stream)
{
    char* ws = (char*)d_ws;
    hipMemsetAsync(d_ws, 0, ZERO_BYTES, stream);   // barrier flags + dtypes + h64 reps

    unsigned* flgs  = (unsigned*)(ws + CNT_OFF);
    unsigned* flags = (unsigned*)(ws + FLG_OFF);
    float*    bs    = (float*)(ws + BS_OFF);
    u64*      h64   = (u64*)(ws + H64_OFF);
    u64*      rh64  = (u64*)(ws + RH64_OFF);
    u16*      xb    = (u16*)(ws + XB_OFF);

    Ptrs dp;
    for (int i = 0; i < 13; i++) dp.p[i] = d_in[i];
    detect_k<<<13, 256, 0, stream>>>(dp, flags);

    SPtrs sp;
    sp.x = d_in[0];
    sp.W[0] = d_in[1];  sp.W[1] = d_in[3];   // Wz, Uz
    sp.W[2] = d_in[5];  sp.W[3] = d_in[7];   // Wr, Ur
    sp.W[4] = d_in[9];  sp.W[5] = d_in[11];  // Wh, Uh
    sp.b[0] = d_in[2];  sp.b[1] = d_in[4];   // bz, cz
    sp.b[2] = d_in[6];  sp.b[3] = d_in[8];   // br, cr
    sp.b[4] = d_in[10]; sp.b[5] = d_in[12];  // bh, ch

    if (ws_size >= WS_FULL) {
        u16* wbuf = (u16*)(ws + WB_OFF);
        stage_k<<<2048 + 6 * 512 + 1, 256, 0, stream>>>(sp, flags, xb, wbuf, bs, 1);
        gru_rec<<<128, 1024, 0, stream>>>(xb, 1, wbuf, bs, h64, rh64, flags, flgs, d_out);
    } else {
        u16* wbuf = (u16*)(ws + XB_OFF);     // no x staging; weights at 1 MB
        stage_k<<<6 * 512 + 1, 256, 0, stream>>>(sp, flags, xb, wbuf, bs, 0);
        gru_rec<<<128, 1024, 0, stream>>>(d_in[0], 0, wbuf, bs, h64, rh64, flags, flgs, d_out);
    }
}

// Round 11
// 1345.667 us; speedup vs baseline: 1.5432x; 1.2532x over previous
//
#include <hip/hip_runtime.h>
#include <stdint.h>

// B=32, T=128, DIN=DOUT=1024. Input dtypes detected at runtime (bf16 vs fp32).
typedef unsigned short u16;
typedef unsigned long long u64;
typedef __attribute__((ext_vector_type(8))) short short8;   // 8 x bf16 MFMA operand
typedef __attribute__((ext_vector_type(4))) float f32x4;    // MFMA accumulator

// ---- workspace layout (bytes) ----
// Anti-contention layout (R5, kept): barrier flags strided 1KB with 4 replicas
// 256B apart; h and r*h tile buffers replicated 4x.
#define CNT_OFF    0                          // barrier flags: 128 x 1KB (zeroed)
#define FLG_OFF    131072                     // 13 dtype flags
#define BS_OFF     135168                     // bias sums fp32: 3*1024*4
#define H64_OFF    147456                     // h bf16 u64[4 rep][32][256]: 256 KB (zeroed)
#define ZERO_BYTES (H64_OFF + 262144)
#define RH64_OFF   ZERO_BYTES                 // r*h u64[4 rep][32][256]: 256 KB (wbr)
#define XB_OFF     (1<<20)                    // x bf16: 8 MB
#define WB_OFF     (9<<20)                    // 6 weight mats bf16: 12 MB
#define WS_FULL    (21u<<20)
#define REP_STRIDE 8192                       // u64 per replica (64 KB)

__device__ __forceinline__ float bf2f(u16 v) {
    unsigned u = ((unsigned)v) << 16;
    return __builtin_bit_cast(float, u);
}
__device__ __forceinline__ u16 f2bf(float f) {
    unsigned u = __builtin_bit_cast(unsigned, f);
    unsigned r = 0x7fffu + ((u >> 16) & 1u);   // RNE
    return (u16)((u + r) >> 16);
}
__device__ __forceinline__ float sigm(float x) { return 1.0f / (1.0f + __expf(-x)); }

__device__ __forceinline__ short8 cvt8f(const float* f) {
    short8 r;
#pragma unroll
    for (int j = 0; j < 8; j++) r[j] = (short)f2bf(f[j]);
    return r;
}
__device__ __forceinline__ short8 cvt8any(const void* src, long ei, unsigned isbf) {
    if (isbf) return *(const short8*)((const u16*)src + ei);
    return cvt8f((const float*)src + ei);
}

__device__ __forceinline__ u64 ld64(const u64* p) {
    return __hip_atomic_load(p, __ATOMIC_RELAXED, __HIP_MEMORY_SCOPE_AGENT);
}
__device__ __forceinline__ unsigned ld_flag(const unsigned* p) {
    return __hip_atomic_load(p, __ATOMIC_RELAXED, __HIP_MEMORY_SCOPE_AGENT);
}
__device__ __forceinline__ void st_flag(unsigned* p, unsigned v) {
    __hip_atomic_store(p, v, __ATOMIC_RELAXED, __HIP_MEMORY_SCOPE_AGENT);
}
__device__ __forceinline__ void st64(u64* p, u64 v) {
    __hip_atomic_store(p, v, __ATOMIC_RELAXED, __HIP_MEMORY_SCOPE_AGENT);
}

// ---- leaderless all-to-all grid barrier (R5/R7, byte-for-byte) ----
// Each block stores a MONOTONE epoch to 4 replica lines of its own 1KB-strided
// flag page; threads 0..NB-1 each poll one block's flag, reading replica
// (blk&3). Ordering: data moves via sc1 atomics (coherent at L3);
// __syncthreads drains vmcnt so all data stores are visible BEFORE the flag
// stores issue; consumer loads are also sc1 so they cannot hit stale L2.
// Flags zeroed once by memset; epochs 1..255 strictly increase per launch.
__device__ __forceinline__ void gbar(unsigned* flgs, unsigned e, unsigned nb) {
    __syncthreads();                 // drains vmcnt: all sc1 data stores at L3
    const unsigned tid = threadIdx.x;
    if (tid < 4)
        st_flag(flgs + blockIdx.x * 256 + tid * 64, e);   // 4 replicas, 256B apart
    if (tid < nb) {
        const unsigned* fp = flgs + tid * 256 + (blockIdx.x & 3) * 64;
        while (ld_flag(fp) < e)
            __builtin_amdgcn_s_sleep(1);
    }
    __syncthreads();
}

struct Ptrs { const void* p[13]; };

// dtype detector: bf16 u16s have exponent in [100,140] (or zero) ~100% for
// N(0,s) data; fp32 read as u16 passes ~58%.
__global__ __launch_bounds__(256) void detect_k(Ptrs ps, unsigned* flags) {
    const u16* a = (const u16*)ps.p[blockIdx.x];
    __shared__ int tot;
    if (threadIdx.x == 0) tot = 0;
    __syncthreads();
    int cnt = 0;
    for (int i = threadIdx.x; i < 1024; i += 256) {
        unsigned u = a[i];
        unsigned e = (u >> 7) & 0xFF;
        cnt += (e == 0 || (e >= 100 && e <= 140)) ? 1 : 0;
    }
    atomicAdd(&tot, cnt);
    __syncthreads();
    if (threadIdx.x == 0) flags[blockIdx.x] = (tot >= 920) ? 1u : 0u;
}

struct SPtrs { const void* x; const void* W[6]; const void* b[6]; };
// W order: Wz,Uz,Wr,Ur,Wh,Uh (flags 1,3,5,7,9,11); b pairs (bz,cz),(br,cr),(bh,ch).

__global__ __launch_bounds__(256) void stage_k(SPtrs ps, const unsigned* __restrict__ flags,
                                               u16* __restrict__ xb, u16* __restrict__ wb,
                                               float* __restrict__ bs, int do_x) {
    int blk = blockIdx.x, tid = threadIdx.x;
    int xblocks = do_x ? 2048 : 0;
    if (blk < xblocks) {                         // x: 4M elems
        long ei = ((long)blk * 256 + tid) * 8;
        *(short8*)(xb + ei) = cvt8any(ps.x, ei, flags[0]);
    } else if (blk < xblocks + 6 * 512) {        // weights: 1M elems each
        int r = (blk - xblocks) >> 9;
        const int fidx[6] = {1, 3, 5, 7, 9, 11};
        long ei = ((long)((blk - xblocks) & 511) * 256 + tid) * 8;
        *(short8*)(wb + (long)r * 1048576 + ei) = cvt8any(ps.W[r], ei, flags[fidx[r]]);
    } else {                                     // bias sums: bs[0]=z, [1]=r, [2]=h
        const int fb[3] = {2, 6, 10}, fc[3] = {4, 8, 12};
        for (int g = 0; g < 3; g++)
            for (int i = tid; i < 1024; i += 256) {
                float b = flags[fb[g]] ? bf2f(((const u16*)ps.b[2 * g])[i])
                                       : ((const float*)ps.b[2 * g])[i];
                float c = flags[fc[g]] ? bf2f(((const u16*)ps.b[2 * g + 1])[i])
                                       : ((const float*)ps.b[2 * g + 1])[i];
                bs[g * 1024 + i] = b + c;
            }
    }
}

// ---- persistent GRU: 128 blocks x 1024 thr (16 waves), K-split chains ----
// Block (ct=blk>>1, rt=blk&1) owns rows R=[16rt,+16) (batch), cols C=[16ct,+16).
// h and r*h live as u64[4 replicas][32][256] (4 bf16 per u64), accessed ONLY
// via sc1 atomics (L3 coherence point). Protocol = R7 (best measured, 1328us;
// R8/R9/R10 protocol restructurings all regressed and are reverted).
//
// R11 change (the R7 pattern applied to phase B): after the mid-step gate,
// all 16 waves cooperatively stage the block's 16 rh rows (32 KB) into LDS
// (reusing the hs buffer - phase A reads are done by then), then phase-B MFMAs
// read operands from LDS. Same sc1 volume as R7's phase B, but the per-wave
// sc1 chain halves (8 -> 4 loads) and issue parallelism doubles (8 -> 16
// waves). This is exactly what R7 did for h (1537 -> 1328).
__global__ __launch_bounds__(1024, 4) void gru_rec(
    const void* __restrict__ xbase, int xmode,   // 1: xbase bf16-staged; 0: raw x
    const u16* __restrict__ wb, const float* __restrict__ bs,
    u64* __restrict__ h64, u64* __restrict__ rh64,
    const unsigned* __restrict__ flags,
    unsigned* __restrict__ flgs,
    void* __restrict__ out)
{
    const int tid  = threadIdx.x;
    const int lane = tid & 63, wave = tid >> 6;      // wave 0..15
    const int quad = lane >> 4, ln = lane & 15;
    const int blk  = blockIdx.x;
    const unsigned NB = gridDim.x;
    const int rep  = blk & 3;                        // data replica this block reads

    const unsigned xisbf = xmode ? 1u : flags[0];
    const unsigned outbf = flags[0];

    const int ct = blk >> 1, rt = blk & 1;
    const int R = rt * 16, C0 = ct * 16;

    // Phase A role: g = wave>>2 (0:hUr 1:xWr 2:hUz 3:xWz), kq = wave&3.
    const int gA  = wave >> 2, kqA = wave & 3;
    const int kb0 = kqA * 256;
    const int wmapA[4] = {3, 2, 1, 0};               // -> Ur, Wr, Uz, Wz
    const u16* BwA = wb + (long)wmapA[gA] * 1048576 + (C0 + ln) * 1024 + kb0 + quad * 8;
    const bool hA  = (gA == 0) || (gA == 2);
    const int hsc  = (kb0 >> 2) + quad * 2;          // hs u64 col base; iter i: +i*8
    const long xAo = ((long)(R + ln) * 128) * 1024 + kb0 + quad * 8; // + t*1024

    // Phase B role: gB = wave>>3 (0:rh@Uh 1:x@Wh), ke = wave&7.
    const int gB  = wave >> 3, keB = wave & 7;
    const int kb1 = keB * 128;
    const u16* BwB = wb + (long)(gB ? 4 : 5) * 1048576 + (C0 + ln) * 1024 + kb1 + quad * 8;
    const int rhsc = (kb1 >> 2) + quad * 2;          // hs u64 col base; iter i: +i*8
    const long xBo = ((long)(R + ln) * 128) * 1024 + kb1 + quad * 8; // + t*1024

    const float bias_z = bs[C0 + ln];
    const float bias_r = bs[1024 + C0 + ln];
    const float bias_h = bs[2048 + C0 + ln];

    __shared__ float sA[16][4][64];    // per-wave partials, conflict-free layout
    __shared__ float zt[4][64];        // z tile
    __shared__ float ht[4][64];        // h fp32 tile (block-private)
    __shared__ u16   tT[16][20];       // transpose staging for u64 packing
    __shared__ __align__(16) u64 hs[16][258];  // staged h rows in phase A, then
                                               // REUSED for rh rows in phase B
                                               // (+2 pad, even stride: 16B align)

    if (wave == 0)
#pragma unroll
        for (int r = 0; r < 4; r++) ht[r][lane] = 0.f;
    __syncthreads();

    const int prow = lane >> 2, pseg = lane & 3;     // packer geometry (wave 0)

    // staging sources: wave w loads row R+w, lane l covers cols l, l+64, l+128, l+192
    const u64* hsrc  = h64  + rep * REP_STRIDE + (R + wave) * 256 + lane;
    const u64* rhsrc = rh64 + rep * REP_STRIDE + (R + wave) * 256 + lane;

    for (int t = 0; t < 128; t++) {
        { // ---- stage h rows into LDS (one sc1 read per word per block) ----
#pragma unroll
            for (int c = 0; c < 4; c++)
                hs[wave][lane + 64 * c] = ld64(hsrc + 64 * c);
        }
        __syncthreads();
        { // ---- phase A chains: 8 MFMAs ----
            f32x4 acc = (f32x4){0.f, 0.f, 0.f, 0.f};
            const long xo = xAo + (long)t * 1024;
#pragma unroll
            for (int i = 0; i < 8; i++) {
                short8 a = hA ? *(const short8*)&hs[ln][hsc + i * 8]
                              : cvt8any(xbase, xo + i * 32, xisbf);
                acc = __builtin_amdgcn_mfma_f32_16x16x32_bf16(
                    a, *(const short8*)(BwA + i * 32), acc, 0, 0, 0);
            }
#pragma unroll
            for (int r = 0; r < 4; r++) sA[wave][r][lane] = acc[r];
        }
        __syncthreads();
        if (wave == 0) {        // r -> r*h, transpose via LDS, publish 4 replicas
#pragma unroll
            for (int r = 0; r < 4; r++) {
                float s = bias_r;
#pragma unroll
                for (int w = 0; w < 8; w++) s += sA[w][r][lane];
                float rv = sigm(s);
                tT[quad * 4 + r][ln] = f2bf(rv * ht[r][lane]);
            }
            u64 v = (u64)tT[prow][pseg * 4] | ((u64)tT[prow][pseg * 4 + 1] << 16)
                  | ((u64)tT[prow][pseg * 4 + 2] << 32) | ((u64)tT[prow][pseg * 4 + 3] << 48);
            u64* dst = &rh64[(R + prow) * 256 + ct * 4 + pseg];
#pragma unroll
            for (int rp = 0; rp < 4; rp++) st64(dst + rp * REP_STRIDE, v);
        } else if (wave == 1) { // z -> LDS
#pragma unroll
            for (int r = 0; r < 4; r++) {
                float s = bias_z;
#pragma unroll
                for (int w = 8; w < 16; w++) s += sA[w][r][lane];
                zt[r][lane] = sigm(s);
            }
        }
        gbar(flgs, 2 * t + 1, NB);
        { // ---- stage rh rows into LDS (R11: all 16 waves, 4 loads each) ----
#pragma unroll
            for (int c = 0; c < 4; c++)
                hs[wave][lane + 64 * c] = ld64(rhsrc + 64 * c);
        }
        __syncthreads();
        { // ---- phase B chains: 4 MFMAs, operands from LDS ----
            f32x4 acc = (f32x4){0.f, 0.f, 0.f, 0.f};
            const long xo = xBo + (long)t * 1024;
#pragma unroll
            for (int i = 0; i < 4; i++) {
                short8 a = (gB == 0) ? *(const short8*)&hs[ln][rhsc + i * 8]
                                     : cvt8any(xbase, xo + i * 32, xisbf);
                acc = __builtin_amdgcn_mfma_f32_16x16x32_bf16(
                    a, *(const short8*)(BwB + i * 32), acc, 0, 0, 0);
            }
#pragma unroll
            for (int r = 0; r < 4; r++) sA[wave][r][lane] = acc[r];
        }
        __syncthreads();
        if (wave == 0) {        // combine: h' = (1-z)h + z*sigm(.), publish h x4
#pragma unroll
            for (int r = 0; r < 4; r++) {
                float s = bias_h;
#pragma unroll
                for (int w = 0; w < 16; w++) s += sA[w][r][lane];
                float hh = sigm(s);
                float z  = zt[r][lane];
                float hv = ht[r][lane];
                float hn = (1.0f - z) * hv + z * hh;
                ht[r][lane] = hn;
                u16 hb = f2bf(hn);
                int row = quad * 4 + r;
                tT[row][ln] = hb;
                long oi = ((long)(t * 32) + R + row) * 1024 + C0 + ln;  // ys (T,B,D)
                if (outbf) ((u16*)out)[oi] = hb;
                else       ((float*)out)[oi] = hn;
            }
            u64 v = (u64)tT[prow][pseg * 4] | ((u64)tT[prow][pseg * 4 + 1] << 16)
                  | ((u64)tT[prow][pseg * 4 + 2] << 32) | ((u64)tT[prow][pseg * 4 + 3] << 48);
            u64* dst = &h64[(R + prow) * 256 + ct * 4 + pseg];
#pragma unroll
            for (int rp = 0; rp < 4; rp++) st64(dst + rp * REP_STRIDE, v);
        }
        if (t < 127) gbar(flgs, 2 * t + 2, NB);
    }
}

extern "C" void kernel_launch(void* const* d_in, const int* in_sizes, int n_in,
                              void* d_out, int out_size, void* d_ws, size_t ws_size,
                              hipStream_t stream)
{
    char* ws = (char*)d_ws;
    hipMemsetAsync(d_ws, 0, ZERO_BYTES, stream);   // barrier flags + dtypes + h64 reps

    unsigned* flgs  = (unsigned*)(ws + CNT_OFF);
    unsigned* flags = (unsigned*)(ws + FLG_OFF);
    float*    bs    = (float*)(ws + BS_OFF);
    u64*      h64   = (u64*)(ws + H64_OFF);
    u64*      rh64  = (u64*)(ws + RH64_OFF);
    u16*      xb    = (u16*)(ws + XB_OFF);

    Ptrs dp;
    for (int i = 0; i < 13; i++) dp.p[i] = d_in[i];
    detect_k<<<13, 256, 0, stream>>>(dp, flags);

    SPtrs sp;
    sp.x = d_in[0];
    sp.W[0] = d_in[1];  sp.W[1] = d_in[3];   // Wz, Uz
    sp.W[2] = d_in[5];  sp.W[3] = d_in[7];   // Wr, Ur
    sp.W[4] = d_in[9];  sp.W[5] = d_in[11];  // Wh, Uh
    sp.b[0] = d_in[2];  sp.b[1] = d_in[4];   // bz, cz
    sp.b[2] = d_in[6];  sp.b[3] = d_in[8];   // br, cr
    sp.b[4] = d_in[10]; sp.b[5] = d_in[12];  // bh, ch

    if (ws_size >= WS_FULL) {
        u16* wbuf = (u16*)(ws + WB_OFF);
        stage_k<<<2048 + 6 * 512 + 1, 256, 0, stream>>>(sp, flags, xb, wbuf, bs, 1);
        gru_rec<<<128, 1024, 0, stream>>>(xb, 1, wbuf, bs, h64, rh64, flags, flgs, d_out);
    } else {
        u16* wbuf = (u16*)(ws + XB_OFF);     // no x staging; weights at 1 MB
        stage_k<<<6 * 512 + 1, 256, 0, stream>>>(sp, flags, xb, wbuf, bs, 0);
        gru_rec<<<128, 1024, 0, stream>>>(d_in[0], 0, wbuf, bs, h64, rh64, flags, flgs, d_out);
    }
}

// Round 12
// 1339.794 us; speedup vs baseline: 1.5499x; 1.0044x over previous
//
#include <hip/hip_runtime.h>
#include <stdint.h>

// B=32, T=128, DIN=DOUT=1024. Input dtypes detected at runtime (bf16 vs fp32).
typedef unsigned short u16;
typedef unsigned long long u64;
typedef __attribute__((ext_vector_type(8))) short short8;   // 8 x bf16 MFMA operand
typedef __attribute__((ext_vector_type(4))) float f32x4;    // MFMA accumulator

// ---- workspace layout (bytes) ----
// Anti-contention layout (R5, kept): barrier flags strided 1KB with 4 replicas
// 256B apart; h and r*h tile buffers replicated 4x.
#define CNT_OFF    0                          // barrier flags: 128 x 1KB (zeroed)
#define FLG_OFF    131072                     // 13 dtype flags
#define BS_OFF     135168                     // bias sums fp32: 3*1024*4
#define H64_OFF    147456                     // h bf16 u64[4 rep][32][256]: 256 KB (zeroed)
#define ZERO_BYTES (H64_OFF + 262144)
#define RH64_OFF   ZERO_BYTES                 // r*h u64[4 rep][32][256]: 256 KB (wbr)
#define XB_OFF     (1<<20)                    // x bf16: 8 MB
#define WB_OFF     (9<<20)                    // 6 weight mats bf16: 12 MB
#define WS_FULL    (21u<<20)
#define REP_STRIDE 8192                       // u64 per replica (64 KB)

__device__ __forceinline__ float bf2f(u16 v) {
    unsigned u = ((unsigned)v) << 16;
    return __builtin_bit_cast(float, u);
}
__device__ __forceinline__ u16 f2bf(float f) {
    unsigned u = __builtin_bit_cast(unsigned, f);
    unsigned r = 0x7fffu + ((u >> 16) & 1u);   // RNE
    return (u16)((u + r) >> 16);
}
__device__ __forceinline__ float sigm(float x) { return 1.0f / (1.0f + __expf(-x)); }

__device__ __forceinline__ short8 cvt8f(const float* f) {
    short8 r;
#pragma unroll
    for (int j = 0; j < 8; j++) r[j] = (short)f2bf(f[j]);
    return r;
}
__device__ __forceinline__ short8 cvt8any(const void* src, long ei, unsigned isbf) {
    if (isbf) return *(const short8*)((const u16*)src + ei);
    return cvt8f((const float*)src + ei);
}

__device__ __forceinline__ u64 ld64(const u64* p) {
    return __hip_atomic_load(p, __ATOMIC_RELAXED, __HIP_MEMORY_SCOPE_AGENT);
}
__device__ __forceinline__ unsigned ld_flag(const unsigned* p) {
    return __hip_atomic_load(p, __ATOMIC_RELAXED, __HIP_MEMORY_SCOPE_AGENT);
}
__device__ __forceinline__ void st_flag(unsigned* p, unsigned v) {
    __hip_atomic_store(p, v, __ATOMIC_RELAXED, __HIP_MEMORY_SCOPE_AGENT);
}
__device__ __forceinline__ void st64(u64* p, u64 v) {
    __hip_atomic_store(p, v, __ATOMIC_RELAXED, __HIP_MEMORY_SCOPE_AGENT);
}

// ---- leaderless all-to-all grid barrier (R5/R7, byte-for-byte) ----
// Each block stores a MONOTONE epoch to 4 replica lines of its own 1KB-strided
// flag page; threads 0..NB-1 each poll one block's flag, reading replica
// (blk&3). Ordering: data moves via sc1 atomics (coherent at L3);
// __syncthreads drains vmcnt so all data stores are visible BEFORE the flag
// stores issue; consumer loads are also sc1 so they cannot hit stale L2.
// Flags zeroed once by memset; epochs 1..255 strictly increase per launch.
__device__ __forceinline__ void gbar(unsigned* flgs, unsigned e, unsigned nb) {
    __syncthreads();                 // drains vmcnt: all sc1 data stores at L3
    const unsigned tid = threadIdx.x;
    if (tid < 4)
        st_flag(flgs + blockIdx.x * 256 + tid * 64, e);   // 4 replicas, 256B apart
    if (tid < nb) {
        const unsigned* fp = flgs + tid * 256 + (blockIdx.x & 3) * 64;
        while (ld_flag(fp) < e)
            __builtin_amdgcn_s_sleep(1);
    }
    __syncthreads();
}

struct Ptrs { const void* p[13]; };

// dtype detector: bf16 u16s have exponent in [100,140] (or zero) ~100% for
// N(0,s) data; fp32 read as u16 passes ~58%.
__global__ __launch_bounds__(256) void detect_k(Ptrs ps, unsigned* flags) {
    const u16* a = (const u16*)ps.p[blockIdx.x];
    __shared__ int tot;
    if (threadIdx.x == 0) tot = 0;
    __syncthreads();
    int cnt = 0;
    for (int i = threadIdx.x; i < 1024; i += 256) {
        unsigned u = a[i];
        unsigned e = (u >> 7) & 0xFF;
        cnt += (e == 0 || (e >= 100 && e <= 140)) ? 1 : 0;
    }
    atomicAdd(&tot, cnt);
    __syncthreads();
    if (threadIdx.x == 0) flags[blockIdx.x] = (tot >= 920) ? 1u : 0u;
}

struct SPtrs { const void* x; const void* W[6]; const void* b[6]; };
// W order: Wz,Uz,Wr,Ur,Wh,Uh (flags 1,3,5,7,9,11); b pairs (bz,cz),(br,cr),(bh,ch).

__global__ __launch_bounds__(256) void stage_k(SPtrs ps, const unsigned* __restrict__ flags,
                                               u16* __restrict__ xb, u16* __restrict__ wb,
                                               float* __restrict__ bs, int do_x) {
    int blk = blockIdx.x, tid = threadIdx.x;
    int xblocks = do_x ? 2048 : 0;
    if (blk < xblocks) {                         // x: 4M elems
        long ei = ((long)blk * 256 + tid) * 8;
        *(short8*)(xb + ei) = cvt8any(ps.x, ei, flags[0]);
    } else if (blk < xblocks + 6 * 512) {        // weights: 1M elems each
        int r = (blk - xblocks) >> 9;
        const int fidx[6] = {1, 3, 5, 7, 9, 11};
        long ei = ((long)((blk - xblocks) & 511) * 256 + tid) * 8;
        *(short8*)(wb + (long)r * 1048576 + ei) = cvt8any(ps.W[r], ei, flags[fidx[r]]);
    } else {                                     // bias sums: bs[0]=z, [1]=r, [2]=h
        const int fb[3] = {2, 6, 10}, fc[3] = {4, 8, 12};
        for (int g = 0; g < 3; g++)
            for (int i = tid; i < 1024; i += 256) {
                float b = flags[fb[g]] ? bf2f(((const u16*)ps.b[2 * g])[i])
                                       : ((const float*)ps.b[2 * g])[i];
                float c = flags[fc[g]] ? bf2f(((const u16*)ps.b[2 * g + 1])[i])
                                       : ((const float*)ps.b[2 * g + 1])[i];
                bs[g * 1024 + i] = b + c;
            }
    }
}

// ---- persistent GRU: 128 blocks x 1024 thr (16 waves), K-split chains ----
// Block (ct=blk>>1, rt=blk&1) owns rows R=[16rt,+16) (batch), cols C=[16ct,+16).
// h and r*h live as u64[4 replicas][32][256] (4 bf16 per u64), accessed ONLY
// via sc1 atomics (L3 coherence point). Protocol + data path = R11 (best,
// 1247us): h AND rh cooperatively staged through LDS, 2 barriers/step.
//
// R12 change (parallelize publisher epilogues): the wave-0 serial chain
// [reduce -> sigm -> pack -> 4 replica stores -> drain] gates flag issuance,
// i.e. the round latency every other block waits on. Waves 2-7 were idle.
// Now: mid-epilogue - waves 0 & 2 duplicate the r-reduce, each storing 2 of
// the 4 rh replicas; end-epilogue - waves 0,1,2 duplicate the combine: wave 0
// updates ht + stores h replicas 0-1, wave 2 stores replicas 2-3, wave 1 owns
// the output stores (off the flag-storing wave's queue). ht is parity
// double-buffered (wave0-write vs wave1/2-read); tT has per-wave copies.
// Store chain per publishing lane: 4 -> 2; drain max drops.
__global__ __launch_bounds__(1024, 4) void gru_rec(
    const void* __restrict__ xbase, int xmode,   // 1: xbase bf16-staged; 0: raw x
    const u16* __restrict__ wb, const float* __restrict__ bs,
    u64* __restrict__ h64, u64* __restrict__ rh64,
    const unsigned* __restrict__ flags,
    unsigned* __restrict__ flgs,
    void* __restrict__ out)
{
    const int tid  = threadIdx.x;
    const int lane = tid & 63, wave = tid >> 6;      // wave 0..15
    const int quad = lane >> 4, ln = lane & 15;
    const int blk  = blockIdx.x;
    const unsigned NB = gridDim.x;
    const int rep  = blk & 3;                        // data replica this block reads

    const unsigned xisbf = xmode ? 1u : flags[0];
    const unsigned outbf = flags[0];

    const int ct = blk >> 1, rt = blk & 1;
    const int R = rt * 16, C0 = ct * 16;

    // Phase A role: g = wave>>2 (0:hUr 1:xWr 2:hUz 3:xWz), kq = wave&3.
    const int gA  = wave >> 2, kqA = wave & 3;
    const int kb0 = kqA * 256;
    const int wmapA[4] = {3, 2, 1, 0};               // -> Ur, Wr, Uz, Wz
    const u16* BwA = wb + (long)wmapA[gA] * 1048576 + (C0 + ln) * 1024 + kb0 + quad * 8;
    const bool hA  = (gA == 0) || (gA == 2);
    const int hsc  = (kb0 >> 2) + quad * 2;          // hs u64 col base; iter i: +i*8
    const long xAo = ((long)(R + ln) * 128) * 1024 + kb0 + quad * 8; // + t*1024

    // Phase B role: gB = wave>>3 (0:rh@Uh 1:x@Wh), ke = wave&7.
    const int gB  = wave >> 3, keB = wave & 7;
    const int kb1 = keB * 128;
    const u16* BwB = wb + (long)(gB ? 4 : 5) * 1048576 + (C0 + ln) * 1024 + kb1 + quad * 8;
    const int rhsc = (kb1 >> 2) + quad * 2;          // hs u64 col base; iter i: +i*8
    const long xBo = ((long)(R + ln) * 128) * 1024 + kb1 + quad * 8; // + t*1024

    const float bias_z = bs[C0 + ln];
    const float bias_r = bs[1024 + C0 + ln];
    const float bias_h = bs[2048 + C0 + ln];

    __shared__ float sA[16][4][64];    // per-wave partials, conflict-free layout
    __shared__ float zt[4][64];        // z tile
    __shared__ float ht[2][4][64];     // h fp32 tile, parity dbuf (R12)
    __shared__ u16   tT[2][16][20];    // transpose staging, per publisher wave (R12)
    __shared__ __align__(16) u64 hs[16][258];  // staged h rows in phase A, then
                                               // REUSED for rh rows in phase B
                                               // (+2 pad, even stride: 16B align)

    if (wave == 0)
#pragma unroll
        for (int r = 0; r < 4; r++) ht[0][r][lane] = 0.f;
    __syncthreads();

    const int prow = lane >> 2, pseg = lane & 3;     // packer geometry

    // staging sources: wave w loads row R+w, lane l covers cols l, l+64, l+128, l+192
    const u64* hsrc  = h64  + rep * REP_STRIDE + (R + wave) * 256 + lane;
    const u64* rhsrc = rh64 + rep * REP_STRIDE + (R + wave) * 256 + lane;

    for (int t = 0; t < 128; t++) {
        const int par = t & 1;                       // ht[par] = h(t)
        { // ---- stage h rows into LDS (one sc1 read per word per block) ----
#pragma unroll
            for (int c = 0; c < 4; c++)
                hs[wave][lane + 64 * c] = ld64(hsrc + 64 * c);
        }
        __syncthreads();
        { // ---- phase A chains: 8 MFMAs ----
            f32x4 acc = (f32x4){0.f, 0.f, 0.f, 0.f};
            const long xo = xAo + (long)t * 1024;
#pragma unroll
            for (int i = 0; i < 8; i++) {
                short8 a = hA ? *(const short8*)&hs[ln][hsc + i * 8]
                              : cvt8any(xbase, xo + i * 32, xisbf);
                acc = __builtin_amdgcn_mfma_f32_16x16x32_bf16(
                    a, *(const short8*)(BwA + i * 32), acc, 0, 0, 0);
            }
#pragma unroll
            for (int r = 0; r < 4; r++) sA[wave][r][lane] = acc[r];
        }
        __syncthreads();
        // ---- mid-epilogue: waves 0 & 2 dup r-reduce, 2 replicas each ----
        if (wave == 0 || wave == 2) {
            const int cp = wave >> 1;                // tT copy / replica pair
#pragma unroll
            for (int r = 0; r < 4; r++) {
                float s = bias_r;
#pragma unroll
                for (int w = 0; w < 8; w++) s += sA[w][r][lane];
                float rv = sigm(s);
                tT[cp][quad * 4 + r][ln] = f2bf(rv * ht[par][r][lane]);
            }
            u64 v = (u64)tT[cp][prow][pseg * 4] | ((u64)tT[cp][prow][pseg * 4 + 1] << 16)
                  | ((u64)tT[cp][prow][pseg * 4 + 2] << 32)
                  | ((u64)tT[cp][prow][pseg * 4 + 3] << 48);
            u64* dst = &rh64[(R + prow) * 256 + ct * 4 + pseg];
            st64(dst + (2 * cp) * REP_STRIDE, v);
            st64(dst + (2 * cp + 1) * REP_STRIDE, v);
        } else if (wave == 1) { // z -> LDS
#pragma unroll
            for (int r = 0; r < 4; r++) {
                float s = bias_z;
#pragma unroll
                for (int w = 8; w < 16; w++) s += sA[w][r][lane];
                zt[r][lane] = sigm(s);
            }
        }
        gbar(flgs, 2 * t + 1, NB);
        { // ---- stage rh rows into LDS (all 16 waves, 4 loads each) ----
#pragma unroll
            for (int c = 0; c < 4; c++)
                hs[wave][lane + 64 * c] = ld64(rhsrc + 64 * c);
        }
        __syncthreads();
        { // ---- phase B chains: 4 MFMAs, operands from LDS ----
            f32x4 acc = (f32x4){0.f, 0.f, 0.f, 0.f};
            const long xo = xBo + (long)t * 1024;
#pragma unroll
            for (int i = 0; i < 4; i++) {
                short8 a = (gB == 0) ? *(const short8*)&hs[ln][rhsc + i * 8]
                                     : cvt8any(xbase, xo + i * 32, xisbf);
                acc = __builtin_amdgcn_mfma_f32_16x16x32_bf16(
                    a, *(const short8*)(BwB + i * 32), acc, 0, 0, 0);
            }
#pragma unroll
            for (int r = 0; r < 4; r++) sA[wave][r][lane] = acc[r];
        }
        __syncthreads();
        // ---- end-epilogue: waves 0,1,2 dup combine; split publish/out ----
        if (wave < 3) {
            float hnv[4];
#pragma unroll
            for (int r = 0; r < 4; r++) {
                float s = bias_h;
#pragma unroll
                for (int w = 0; w < 16; w++) s += sA[w][r][lane];
                float hh = sigm(s);
                float z  = zt[r][lane];
                float hv = ht[par][r][lane];
                hnv[r] = (1.0f - z) * hv + z * hh;
            }
            if (wave == 1) {          // output stores (off the publisher waves)
#pragma unroll
                for (int r = 0; r < 4; r++) {
                    int row = quad * 4 + r;
                    long oi = ((long)(t * 32) + R + row) * 1024 + C0 + ln; // ys (T,B,D)
                    if (outbf) ((u16*)out)[oi] = f2bf(hnv[r]);
                    else       ((float*)out)[oi] = hnv[r];
                }
            } else {                  // waves 0,2: publish 2 replicas each
                const int cp = wave >> 1;
#pragma unroll
                for (int r = 0; r < 4; r++) {
                    if (wave == 0) ht[par ^ 1][r][lane] = hnv[r];
                    tT[cp][quad * 4 + r][ln] = f2bf(hnv[r]);
                }
                u64 v = (u64)tT[cp][prow][pseg * 4] | ((u64)tT[cp][prow][pseg * 4 + 1] << 16)
                      | ((u64)tT[cp][prow][pseg * 4 + 2] << 32)
                      | ((u64)tT[cp][prow][pseg * 4 + 3] << 48);
                u64* dst = &h64[(R + prow) * 256 + ct * 4 + pseg];
                st64(dst + (2 * cp) * REP_STRIDE, v);
                st64(dst + (2 * cp + 1) * REP_STRIDE, v);
            }
        }
        if (t < 127) gbar(flgs, 2 * t + 2, NB);
    }
}

extern "C" void kernel_launch(void* const* d_in, const int* in_sizes, int n_in,
                              void* d_out, int out_size, void* d_ws, size_t ws_size,
                              hipStream_t stream)
{
    char* ws = (char*)d_ws;
    hipMemsetAsync(d_ws, 0, ZERO_BYTES, stream);   // barrier flags + dtypes + h64 reps

    unsigned* flgs  = (unsigned*)(ws + CNT_OFF);
    unsigned* flags = (unsigned*)(ws + FLG_OFF);
    float*    bs    = (float*)(ws + BS_OFF);
    u64*      h64   = (u64*)(ws + H64_OFF);
    u64*      rh64  = (u64*)(ws + RH64_OFF);
    u16*      xb    = (u16*)(ws + XB_OFF);

    Ptrs dp;
    for (int i = 0; i < 13; i++) dp.p[i] = d_in[i];
    detect_k<<<13, 256, 0, stream>>>(dp, flags);

    SPtrs sp;
    sp.x = d_in[0];
    sp.W[0] = d_in[1];  sp.W[1] = d_in[3];   // Wz, Uz
    sp.W[2] = d_in[5];  sp.W[3] = d_in[7];   // Wr, Ur
    sp.W[4] = d_in[9];  sp.W[5] = d_in[11];  // Wh, Uh
    sp.b[0] = d_in[2];  sp.b[1] = d_in[4];   // bz, cz
    sp.b[2] = d_in[6];  sp.b[3] = d_in[8];   // br, cr
    sp.b[4] = d_in[10]; sp.b[5] = d_in[12];  // bh, ch

    if (ws_size >= WS_FULL) {
        u16* wbuf = (u16*)(ws + WB_OFF);
        stage_k<<<2048 + 6 * 512 + 1, 256, 0, stream>>>(sp, flags, xb, wbuf, bs, 1);
        gru_rec<<<128, 1024, 0, stream>>>(xb, 1, wbuf, bs, h64, rh64, flags, flgs, d_out);
    } else {
        u16* wbuf = (u16*)(ws + XB_OFF);     // no x staging; weights at 1 MB
        stage_k<<<6 * 512 + 1, 256, 0, stream>>>(sp, flags, xb, wbuf, bs, 0);
        gru_rec<<<128, 1024, 0, stream>>>(d_in[0], 0, wbuf, bs, h64, rh64, flags, flgs, d_out);
    }
}